// Round 6
// baseline (376.342 us; speedup 1.0000x reference)
//
#include <hip/hip_runtime.h>

#define NBATCH 16
#define CCH 256
#define NTOK 2304

typedef __attribute__((ext_vector_type(8))) short bf16x8;
typedef __attribute__((ext_vector_type(4))) short bf16x4v;
typedef __attribute__((ext_vector_type(4))) float f32x4;

__device__ __forceinline__ short f2bf(float x){
  unsigned u = __builtin_bit_cast(unsigned, x);
  u = u + 0x7FFFu + ((u >> 16) & 1u);
  return (short)(u >> 16);
}

__device__ __forceinline__ void gld_lds16(const short* g, short* l){
  __builtin_amdgcn_global_load_lds((const __attribute__((address_space(1))) void*)g,
                                   (__attribute__((address_space(3))) void*)l, 16, 0, 0);
}

// ---------------- weights fp32 -> bf16 ----------------
__global__ __launch_bounds__(256) void cw_kernel(const float* __restrict__ Wq, const float* __restrict__ Wk,
                                                 const float* __restrict__ Wv, const float* __restrict__ Wo,
                                                 short* __restrict__ out){
  int idx = blockIdx.x * 256 + threadIdx.x;
  int which = idx >> 14;
  int off = idx & 16383;
  const float* src = which==0 ? Wq : which==1 ? Wk : which==2 ? Wv : Wo;
  float4 v = ((const float4*)src)[off];
  bf16x4v pk = { f2bf(v.x), f2bf(v.y), f2bf(v.z), f2bf(v.w) };
  *(bf16x4v*)(out + ((size_t)which << 16) + ((size_t)off << 2)) = pk;
}

// ---------------- transpose+convert [C][N] f32 -> [N][C] bf16 ----------------
__global__ __launch_bounds__(256) void prep_kernel(const float* __restrict__ img, const float* __restrict__ msk,
                                                   short* __restrict__ imgT, short* __restrict__ mskT){
  int zz = blockIdx.z; int b = zz >> 1; int which = zz & 1;
  const float* src = (which ? msk : img) + (size_t)b * CCH * NTOK;
  short* dst = (which ? mskT : imgT) + (size_t)b * NTOK * CCH;
  int n0 = blockIdx.x * 64, c0 = blockIdx.y * 64;
  __shared__ __align__(16) short tile[64][72];
  int tid = threadIdx.x;
  int r = tid >> 2, g = tid & 3;
  const float* p = src + (size_t)(c0 + r) * NTOK + n0 + 16 * g;
  #pragma unroll
  for (int q4 = 0; q4 < 4; q4++){
    float4 v = *(const float4*)(p + 4 * q4);
    tile[16*g + 4*q4 + 0][r] = f2bf(v.x);
    tile[16*g + 4*q4 + 1][r] = f2bf(v.y);
    tile[16*g + 4*q4 + 2][r] = f2bf(v.z);
    tile[16*g + 4*q4 + 3][r] = f2bf(v.w);
  }
  __syncthreads();
  short* qp = dst + (size_t)(n0 + r) * CCH + c0 + 16 * g;
  *(bf16x8*)qp = *(const bf16x8*)&tile[r][16*g];
  *(bf16x8*)(qp + 8) = *(const bf16x8*)&tile[r][16*g + 8];
}

// ---------------- 128x128 GEMM core ----------------
__device__ __forceinline__ void gemm128(const short* __restrict__ Ablk, const short* __restrict__ Bblk,
                                        short* As, short* Bs, f32x4 (&acc)[4][4]){
  const int tid = threadIdx.x;
  const int l = tid & 63, w = tid >> 6;
  const int l15 = l & 15, lhi = l >> 4;
  const int wi = w >> 1, wj = w & 1;
  const int srow = tid >> 3, scs = tid & 7;
  const f32x4 z4 = {0.f, 0.f, 0.f, 0.f};
  #pragma unroll
  for (int mt = 0; mt < 4; mt++)
    #pragma unroll
    for (int nt = 0; nt < 4; nt++) acc[mt][nt] = z4;

  #pragma unroll 1
  for (int kt = 0; kt < 4; kt++){
    const int k0 = kt * 64;
    bf16x8 ra[4], rb[4];
    #pragma unroll
    for (int p = 0; p < 4; p++){
      const int row = p * 32 + srow;
      ra[p] = *(const bf16x8*)(Ablk + (size_t)row * CCH + k0 + 8 * scs);
      rb[p] = *(const bf16x8*)(Bblk + (size_t)row * CCH + k0 + 8 * scs);
    }
    __syncthreads();
    #pragma unroll
    for (int p = 0; p < 4; p++){
      const int row = p * 32 + srow;
      const int sw = (scs ^ (row & 7)) << 3;
      *(bf16x8*)(As + row * 64 + sw) = ra[p];
      *(bf16x8*)(Bs + row * 64 + sw) = rb[p];
    }
    __syncthreads();
    #pragma unroll
    for (int kk = 0; kk < 2; kk++){
      bf16x8 afr[4], bfr[4];
      #pragma unroll
      for (int mt = 0; mt < 4; mt++){
        const int row = 64 * wi + 16 * mt + l15;
        const int ch = 4 * kk + lhi;
        afr[mt] = *(const bf16x8*)(As + row * 64 + ((ch ^ (row & 7)) << 3));
      }
      #pragma unroll
      for (int nt = 0; nt < 4; nt++){
        const int row = 64 * wj + 16 * nt + l15;
        const int ch = 4 * kk + lhi;
        bfr[nt] = *(const bf16x8*)(Bs + row * 64 + ((ch ^ (row & 7)) << 3));
      }
      #pragma unroll
      for (int mt = 0; mt < 4; mt++)
        #pragma unroll
        for (int nt = 0; nt < 4; nt++)
          acc[mt][nt] = __builtin_amdgcn_mfma_f32_16x16x32_bf16(afr[mt], bfr[nt], acc[mt][nt], 0, 0, 0);
    }
  }
}

// ---------------- QKV projections ----------------
// Q carries scale/16 AND log2(e) so attention can use raw v_exp (exp2).
__global__ __launch_bounds__(256) void proj_kernel(const short* __restrict__ imgT, const short* __restrict__ mskT,
                                                   const short* __restrict__ Wb,
                                                   const float* __restrict__ bq, const float* __restrict__ bk,
                                                   const float* __restrict__ bv,
                                                   short* __restrict__ Qt, short* __restrict__ Kt,
                                                   short* __restrict__ Vn){
  __shared__ __align__(16) short As[128 * 64];
  __shared__ __align__(16) short Bs[128 * 64];
  const int b = blockIdx.z, which = blockIdx.y, bx = blockIdx.x;
  const size_t nbT = (size_t)b * NTOK * CCH;
  const short* Ablk; const short* Bblk; short* outp; const float* bias;
  int ti, tj, ldout; bool biasRow; float scl;
  if (which == 0){
    ti = bx >> 1; tj = bx & 1;
    Ablk = mskT + nbT + (size_t)ti * 128 * CCH;
    Bblk = Wb + (size_t)tj * 128 * CCH;
    outp = Qt + nbT; bias = bq; ldout = CCH; biasRow = false;
    scl = 0.0625f * 1.44269504088896f;   // 1/sqrt(256) * log2(e)
  } else if (which == 1){
    ti = bx >> 1; tj = bx & 1;
    Ablk = imgT + nbT + (size_t)ti * 128 * CCH;
    Bblk = Wb + 65536 + (size_t)tj * 128 * CCH;
    outp = Kt + nbT; bias = bk; ldout = CCH; biasRow = false; scl = 1.0f;
  } else {
    ti = bx / 18; tj = bx % 18;
    Ablk = Wb + 2 * 65536 + (size_t)ti * 128 * CCH;
    Bblk = imgT + nbT + (size_t)tj * 128 * CCH;
    outp = Vn + nbT; bias = bv; ldout = NTOK; biasRow = true; scl = 1.0f;
  }
  f32x4 acc[4][4];
  gemm128(Ablk, Bblk, As, Bs, acc);
  const int l = threadIdx.x & 63, w = threadIdx.x >> 6;
  const int l15 = l & 15, lhi = l >> 4, wi = w >> 1, wj = w & 1;
  #pragma unroll
  for (int mt = 0; mt < 4; mt++){
    const int i0 = ti * 128 + 64 * wi + 16 * mt + 4 * lhi;
    #pragma unroll
    for (int nt = 0; nt < 4; nt++){
      const int j = tj * 128 + 64 * wj + 16 * nt + l15;
      const float bj = biasRow ? 0.f : bias[j];
      #pragma unroll
      for (int r = 0; r < 4; r++){
        float v = acc[mt][nt][r] + (biasRow ? bias[i0 + r] : bj);
        outp[(size_t)(i0 + r) * ldout + j] = f2bf(v * scl);
      }
    }
  }
}

// ---------------- attention, no-max softmax, counted barriers ----------------
// BAR1: s_waitcnt vmcnt(8) + s_barrier  (K stage done, V loads keep flying)
// BAR2: s_waitcnt lgkmcnt(0) + s_barrier (P visible, Ks reads done; NO vmcnt drain)
// P_lds [64][64] with chunk-XOR swizzle -> pf ds_read_b128 conflict-free.
__global__ __launch_bounds__(256) void attn_kernel(const short* __restrict__ Qt, const short* __restrict__ Kt,
                                                   const short* __restrict__ Vn, short* __restrict__ avT){
  const int phys = blockIdx.x;
  const int L = (phys & 7) * 72 + (phys >> 3);   // 576 = 8*72, bijective XCD grouping
  const int b = L / 36;
  const int q0 = (L % 36) * 64;
  const int tid = threadIdx.x, w = tid >> 6, l = tid & 63;
  const int l15 = l & 15, lhi = l >> 4;
  const short* Qb = Qt + (size_t)b * NTOK * CCH;
  const short* Kb = Kt + (size_t)b * NTOK * CCH;
  const short* Vb = Vn + (size_t)b * CCH * NTOK;
  __shared__ __align__(16) short Ks[64 * 256];      // 32 KB
  __shared__ __align__(16) short P_lds[64 * 64];    // 8 KB, swizzled; total LDS = 40 KB

  const int st_row = (l >> 5);
  const int st_ch  = (l & 31);

  bf16x8 qf[8];
  {
    const short* qrow = Qb + (size_t)(q0 + 16 * w + l15) * CCH + 8 * lhi;
    #pragma unroll
    for (int kk = 0; kk < 8; kk++) qf[kk] = *(const bf16x8*)(qrow + 32 * kk);
  }
  const f32x4 z4 = {0.f, 0.f, 0.f, 0.f};
  f32x4 oacc[4][4];
  #pragma unroll
  for (int qt = 0; qt < 4; qt++)
    #pragma unroll
    for (int ct = 0; ct < 4; ct++) oacc[qt][ct] = z4;
  float lpart[4] = {0.f, 0.f, 0.f, 0.f};

#define STAGE_K(M0) do { \
    _Pragma("unroll") \
    for (int r = 0; r < 8; r++){ \
      const int slot = 4 * r + w; \
      const int row = 2 * slot + st_row; \
      const int ch = st_ch ^ (row & 7); \
      gld_lds16(Kb + (size_t)((M0) + row) * CCH + (ch << 3), &Ks[slot * 512]); \
    } } while(0)

#define LOAD_V(VFP, M0) do { \
    _Pragma("unroll") \
    for (int km = 0; km < 2; km++) \
      _Pragma("unroll") \
      for (int ct = 0; ct < 4; ct++) \
        VFP[4*km+ct] = *(const bf16x8*)(Vb + (size_t)(64*w + 16*ct + l15) * NTOK + (M0) + 32*km + 8*lhi); \
    } while(0)

  bf16x8 vfp[8];
  // prologue: K(0) then V(0) -> at BAR1 the 8 oldest (K) must land, V can fly
  STAGE_K(0);
  LOAD_V(vfp, 0);

  #pragma unroll 1
  for (int t = 0; t < 36; t++){
    const int m0 = t * 64;
    // ---- BAR1: K(t) staged; V(t) loads may still be in flight ----
    asm volatile("s_waitcnt vmcnt(8)" ::: "memory");
    __builtin_amdgcn_sched_barrier(0);
    __builtin_amdgcn_s_barrier();
    __builtin_amdgcn_sched_barrier(0);

    // S = Q·K^T from LDS (swizzled reads)
    f32x4 sacc[4] = {z4, z4, z4, z4};
    __builtin_amdgcn_s_setprio(1);
    #pragma unroll
    for (int mjb = 0; mjb < 4; mjb++){
      const int row = 16 * mjb + l15;
      const int rsw = row & 7;
      #pragma unroll
      for (int kk = 0; kk < 8; kk++){
        bf16x8 kf = *(const bf16x8*)(Ks + row * 256 + (((4 * kk + lhi) ^ rsw) << 3));
        sacc[mjb] = __builtin_amdgcn_mfma_f32_16x16x32_bf16(qf[kk], kf, sacc[mjb], 0, 0, 0);
      }
    }
    __builtin_amdgcn_s_setprio(0);
    // P = exp2(s'); per-lane partial row sums; swizzled P_lds write
    #pragma unroll
    for (int mjb = 0; mjb < 4; mjb++)
      #pragma unroll
      for (int r = 0; r < 4; r++){
        float p = exp2f(sacc[mjb][r]);
        lpart[r] += p;
        const int prow = 16 * w + 4 * lhi + r;
        const int pcol = 16 * mjb + l15;
        P_lds[prow * 64 + ((((pcol >> 3) ^ (prow & 7)) << 3) | (pcol & 7))] = f2bf(p);
      }
    // ---- BAR2: P visible + all Ks reads done; no vmcnt drain ----
    asm volatile("s_waitcnt lgkmcnt(0)" ::: "memory");
    __builtin_amdgcn_sched_barrier(0);
    __builtin_amdgcn_s_barrier();
    __builtin_amdgcn_sched_barrier(0);

    // stage K(t+1) now; lands during PV + BAR1 wait of next iter
    if (t + 1 < 36) STAGE_K(m0 + 64);

    // O += P · V^T (P from swizzled LDS, V from prefetched regs)
    __builtin_amdgcn_s_setprio(1);
    #pragma unroll
    for (int km = 0; km < 2; km++){
      bf16x8 pf[4];
      #pragma unroll
      for (int qt = 0; qt < 4; qt++){
        const int prow = 16 * qt + l15;
        pf[qt] = *(const bf16x8*)&P_lds[prow * 64 + (((4 * km + lhi) ^ (prow & 7)) << 3)];
      }
      #pragma unroll
      for (int qt = 0; qt < 4; qt++)
        #pragma unroll
        for (int ct = 0; ct < 4; ct++)
          oacc[qt][ct] = __builtin_amdgcn_mfma_f32_16x16x32_bf16(pf[qt], vfp[4 * km + ct], oacc[qt][ct], 0, 0, 0);
    }
    __builtin_amdgcn_s_setprio(0);

    // V(t+1) prefetch: crosses both barriers (never drained), consumed next PV
    if (t + 1 < 36) LOAD_V(vfp, m0 + 64);
  }
#undef STAGE_K
#undef LOAD_V

  __syncthreads();   // all PV reads of P_lds done before lsum aliases it
  float* lsum_lds = (float*)P_lds;
  #pragma unroll
  for (int r = 0; r < 4; r++){
    float s = lpart[r];
    s += __shfl_xor(s, 1); s += __shfl_xor(s, 2); s += __shfl_xor(s, 4); s += __shfl_xor(s, 8);
    if (l15 == 0) lsum_lds[16 * w + 4 * lhi + r] = s;
  }
  __syncthreads();
  short* avb = avT + (size_t)b * NTOK * CCH;
  #pragma unroll
  for (int qt = 0; qt < 4; qt++){
    f32x4 lv = *(const f32x4*)&lsum_lds[16 * qt + 4 * lhi];
    f32x4 inv;
    #pragma unroll
    for (int r = 0; r < 4; r++) inv[r] = 1.0f / lv[r];
    #pragma unroll
    for (int ct = 0; ct < 4; ct++)
      #pragma unroll
      for (int r = 0; r < 4; r++)
        avb[(size_t)(q0 + 16 * qt + 4 * lhi + r) * CCH + 64 * w + 16 * ct + l15] =
            f2bf(oacc[qt][ct][r] * inv[r]);
  }
}

// ---------------- final: out = image + Wo·av + bo ----------------
__global__ __launch_bounds__(256) void final_kernel(const short* __restrict__ Wb, const short* __restrict__ avT,
                                                    const float* __restrict__ bo, const float* __restrict__ img,
                                                    float* __restrict__ out){
  __shared__ __align__(16) short As[128 * 64];
  __shared__ __align__(16) short Bs[128 * 64];
  const int b = blockIdx.y, bx = blockIdx.x;
  const int ti = bx / 18, tj = bx % 18;
  const short* Ablk = Wb + 3 * 65536 + (size_t)ti * 128 * CCH;
  const short* Bblk = avT + (size_t)b * NTOK * CCH + (size_t)tj * 128 * CCH;
  f32x4 acc[4][4];
  gemm128(Ablk, Bblk, As, Bs, acc);
  const int l = threadIdx.x & 63, w = threadIdx.x >> 6;
  const int l15 = l & 15, lhi = l >> 4, wi = w >> 1, wj = w & 1;
  const float* imgb = img + (size_t)b * CCH * NTOK;
  float* outb = out + (size_t)b * CCH * NTOK;
  #pragma unroll
  for (int mt = 0; mt < 4; mt++){
    const int i0 = ti * 128 + 64 * wi + 16 * mt + 4 * lhi;
    #pragma unroll
    for (int nt = 0; nt < 4; nt++){
      const int j = tj * 128 + 64 * wj + 16 * nt + l15;
      #pragma unroll
      for (int r = 0; r < 4; r++){
        const size_t idx = (size_t)(i0 + r) * NTOK + j;
        outb[idx] = acc[mt][nt][r] + bo[i0 + r] + imgb[idx];
      }
    }
  }
}

extern "C" void kernel_launch(void* const* d_in, const int* in_sizes, int n_in,
                              void* d_out, int out_size, void* d_ws, size_t ws_size,
                              hipStream_t stream) {
  const float* img = (const float*)d_in[0];
  const float* msk = (const float*)d_in[1];
  const float* Wq  = (const float*)d_in[2];
  const float* bq  = (const float*)d_in[3];
  const float* Wk  = (const float*)d_in[4];
  const float* bk  = (const float*)d_in[5];
  const float* Wv  = (const float*)d_in[6];
  const float* bv  = (const float*)d_in[7];
  const float* Wo  = (const float*)d_in[8];
  const float* bo  = (const float*)d_in[9];
  float* out = (float*)d_out;

  short* ws = (short*)d_ws;
  const size_t NE = (size_t)NBATCH * NTOK * CCH;
  short* imgT = ws;
  short* mskT = ws + NE;
  short* Qt   = ws + 2 * NE;
  short* Kt   = ws + 3 * NE;
  short* Vn   = ws + 4 * NE;
  short* Wb   = ws + 5 * NE;
  short* avT  = mskT;              // reuse: mskT consumed before attn writes avT

  cw_kernel<<<dim3(256), dim3(256), 0, stream>>>(Wq, Wk, Wv, Wo, Wb);
  prep_kernel<<<dim3(36, 4, 32), dim3(256), 0, stream>>>(img, msk, imgT, mskT);
  proj_kernel<<<dim3(36, 3, 16), dim3(256), 0, stream>>>(imgT, mskT, Wb, bq, bk, bv, Qt, Kt, Vn);
  attn_kernel<<<dim3(576), dim3(256), 0, stream>>>(Qt, Kt, Vn, avT);
  final_kernel<<<dim3(36, 16), dim3(256), 0, stream>>>(Wb, avT, bo, img, out);
}

// Round 7
// 250.213 us; speedup vs baseline: 1.5041x; 1.5041x over previous
//
#include <hip/hip_runtime.h>

#define NBATCH 16
#define CCH 256
#define NTOK 2304

typedef __attribute__((ext_vector_type(8))) short bf16x8;
typedef __attribute__((ext_vector_type(4))) short bf16x4v;
typedef __attribute__((ext_vector_type(4))) float f32x4;

__device__ __forceinline__ short f2bf(float x){
  unsigned u = __builtin_bit_cast(unsigned, x);
  u = u + 0x7FFFu + ((u >> 16) & 1u);
  return (short)(u >> 16);
}
__device__ __forceinline__ float bf2f(short h){
  unsigned u = ((unsigned)(unsigned short)h) << 16;
  return __builtin_bit_cast(float, u);
}

__device__ __forceinline__ void gld_lds16(const short* g, short* l){
  __builtin_amdgcn_global_load_lds((const __attribute__((address_space(1))) void*)g,
                                   (__attribute__((address_space(3))) void*)l, 16, 0, 0);
}

// ---------------- weights fp32 -> bf16 ----------------
__global__ __launch_bounds__(256) void cw_kernel(const float* __restrict__ Wq, const float* __restrict__ Wk,
                                                 const float* __restrict__ Wv, const float* __restrict__ Wo,
                                                 short* __restrict__ out){
  int idx = blockIdx.x * 256 + threadIdx.x;
  int which = idx >> 14;
  int off = idx & 16383;
  const float* src = which==0 ? Wq : which==1 ? Wk : which==2 ? Wv : Wo;
  float4 v = ((const float4*)src)[off];
  bf16x4v pk = { f2bf(v.x), f2bf(v.y), f2bf(v.z), f2bf(v.w) };
  *(bf16x4v*)(out + ((size_t)which << 16) + ((size_t)off << 2)) = pk;
}

// ---------------- transpose+convert [C][N] f32 -> [N][C] bf16 ----------------
__global__ __launch_bounds__(256) void prep_kernel(const float* __restrict__ img, const float* __restrict__ msk,
                                                   short* __restrict__ imgT, short* __restrict__ mskT){
  int zz = blockIdx.z; int b = zz >> 1; int which = zz & 1;
  const float* src = (which ? msk : img) + (size_t)b * CCH * NTOK;
  short* dst = (which ? mskT : imgT) + (size_t)b * NTOK * CCH;
  int n0 = blockIdx.x * 64, c0 = blockIdx.y * 64;
  __shared__ __align__(16) short tile[64][72];
  int tid = threadIdx.x;
  int r = tid >> 2, g = tid & 3;
  const float* p = src + (size_t)(c0 + r) * NTOK + n0 + 16 * g;
  #pragma unroll
  for (int q4 = 0; q4 < 4; q4++){
    float4 v = *(const float4*)(p + 4 * q4);
    tile[16*g + 4*q4 + 0][r] = f2bf(v.x);
    tile[16*g + 4*q4 + 1][r] = f2bf(v.y);
    tile[16*g + 4*q4 + 2][r] = f2bf(v.z);
    tile[16*g + 4*q4 + 3][r] = f2bf(v.w);
  }
  __syncthreads();
  short* qp = dst + (size_t)(n0 + r) * CCH + c0 + 16 * g;
  *(bf16x8*)qp = *(const bf16x8*)&tile[r][16*g];
  *(bf16x8*)(qp + 8) = *(const bf16x8*)&tile[r][16*g + 8];
}

// ---------------- 128x128 GEMM core ----------------
__device__ __forceinline__ void gemm128(const short* __restrict__ Ablk, const short* __restrict__ Bblk,
                                        short* As, short* Bs, f32x4 (&acc)[4][4]){
  const int tid = threadIdx.x;
  const int l = tid & 63, w = tid >> 6;
  const int l15 = l & 15, lhi = l >> 4;
  const int wi = w >> 1, wj = w & 1;
  const int srow = tid >> 3, scs = tid & 7;
  const f32x4 z4 = {0.f, 0.f, 0.f, 0.f};
  #pragma unroll
  for (int mt = 0; mt < 4; mt++)
    #pragma unroll
    for (int nt = 0; nt < 4; nt++) acc[mt][nt] = z4;

  #pragma unroll 1
  for (int kt = 0; kt < 4; kt++){
    const int k0 = kt * 64;
    bf16x8 ra[4], rb[4];
    #pragma unroll
    for (int p = 0; p < 4; p++){
      const int row = p * 32 + srow;
      ra[p] = *(const bf16x8*)(Ablk + (size_t)row * CCH + k0 + 8 * scs);
      rb[p] = *(const bf16x8*)(Bblk + (size_t)row * CCH + k0 + 8 * scs);
    }
    __syncthreads();
    #pragma unroll
    for (int p = 0; p < 4; p++){
      const int row = p * 32 + srow;
      const int sw = (scs ^ (row & 7)) << 3;
      *(bf16x8*)(As + row * 64 + sw) = ra[p];
      *(bf16x8*)(Bs + row * 64 + sw) = rb[p];
    }
    __syncthreads();
    #pragma unroll
    for (int kk = 0; kk < 2; kk++){
      bf16x8 afr[4], bfr[4];
      #pragma unroll
      for (int mt = 0; mt < 4; mt++){
        const int row = 64 * wi + 16 * mt + l15;
        const int ch = 4 * kk + lhi;
        afr[mt] = *(const bf16x8*)(As + row * 64 + ((ch ^ (row & 7)) << 3));
      }
      #pragma unroll
      for (int nt = 0; nt < 4; nt++){
        const int row = 64 * wj + 16 * nt + l15;
        const int ch = 4 * kk + lhi;
        bfr[nt] = *(const bf16x8*)(Bs + row * 64 + ((ch ^ (row & 7)) << 3));
      }
      #pragma unroll
      for (int mt = 0; mt < 4; mt++)
        #pragma unroll
        for (int nt = 0; nt < 4; nt++)
          acc[mt][nt] = __builtin_amdgcn_mfma_f32_16x16x32_bf16(afr[mt], bfr[nt], acc[mt][nt], 0, 0, 0);
    }
  }
}

// ---------------- QKV projections ----------------
// Q carries scale/16 AND log2(e) so attention can use raw exp2.
__global__ __launch_bounds__(256) void proj_kernel(const short* __restrict__ imgT, const short* __restrict__ mskT,
                                                   const short* __restrict__ Wb,
                                                   const float* __restrict__ bq, const float* __restrict__ bk,
                                                   const float* __restrict__ bv,
                                                   short* __restrict__ Qt, short* __restrict__ Kt,
                                                   short* __restrict__ Vn){
  __shared__ __align__(16) short As[128 * 64];
  __shared__ __align__(16) short Bs[128 * 64];
  const int b = blockIdx.z, which = blockIdx.y, bx = blockIdx.x;
  const size_t nbT = (size_t)b * NTOK * CCH;
  const short* Ablk; const short* Bblk; short* outp; const float* bias;
  int ti, tj, ldout; bool biasRow; float scl;
  if (which == 0){
    ti = bx >> 1; tj = bx & 1;
    Ablk = mskT + nbT + (size_t)ti * 128 * CCH;
    Bblk = Wb + (size_t)tj * 128 * CCH;
    outp = Qt + nbT; bias = bq; ldout = CCH; biasRow = false;
    scl = 0.0625f * 1.44269504088896f;   // 1/sqrt(256) * log2(e)
  } else if (which == 1){
    ti = bx >> 1; tj = bx & 1;
    Ablk = imgT + nbT + (size_t)ti * 128 * CCH;
    Bblk = Wb + 65536 + (size_t)tj * 128 * CCH;
    outp = Kt + nbT; bias = bk; ldout = CCH; biasRow = false; scl = 1.0f;
  } else {
    ti = bx / 18; tj = bx % 18;
    Ablk = Wb + 2 * 65536 + (size_t)ti * 128 * CCH;
    Bblk = imgT + nbT + (size_t)tj * 128 * CCH;
    outp = Vn + nbT; bias = bv; ldout = NTOK; biasRow = true; scl = 1.0f;
  }
  f32x4 acc[4][4];
  gemm128(Ablk, Bblk, As, Bs, acc);
  const int l = threadIdx.x & 63, w = threadIdx.x >> 6;
  const int l15 = l & 15, lhi = l >> 4, wi = w >> 1, wj = w & 1;
  #pragma unroll
  for (int mt = 0; mt < 4; mt++){
    const int i0 = ti * 128 + 64 * wi + 16 * mt + 4 * lhi;
    #pragma unroll
    for (int nt = 0; nt < 4; nt++){
      const int j = tj * 128 + 64 * wj + 16 * nt + l15;
      const float bj = biasRow ? 0.f : bias[j];
      #pragma unroll
      for (int r = 0; r < 4; r++){
        float v = acc[mt][nt][r] + (biasRow ? bias[i0 + r] : bj);
        outp[(size_t)(i0 + r) * ldout + j] = f2bf(v * scl);
      }
    }
  }
}

// ---------------- attention, split-KV x2, no-max softmax ----------------
// R5 skeleton (plain __syncthreads, V reg-prefetch at top, STAGE after BAR2).
// Each block does 18 of 36 KV tiles; partial O (bf16, unnormalized) -> Opart,
// partial row-sums -> lsumg. LDS exactly 40 KB -> 4 blocks/CU (16 waves/CU).
__global__ __launch_bounds__(256) void attn_kernel(const short* __restrict__ Qt, const short* __restrict__ Kt,
                                                   const short* __restrict__ Vn,
                                                   short* __restrict__ Opart, float* __restrict__ lsumg){
  const int phys = blockIdx.x;
  const int L = (phys & 7) * 144 + (phys >> 3);   // 1152 = 8*144; 144 = 2 batches/XCD
  const int b = L / 72;
  const int rem = L % 72;
  const int half = rem / 36;
  const int q0 = (rem % 36) * 64;
  const int t0 = half * 18;
  const int tid = threadIdx.x, w = tid >> 6, l = tid & 63;
  const int l15 = l & 15, lhi = l >> 4;
  const short* Qb = Qt + (size_t)b * NTOK * CCH;
  const short* Kb = Kt + (size_t)b * NTOK * CCH;
  const short* Vb = Vn + (size_t)b * CCH * NTOK;
  __shared__ __align__(16) short Ks[64 * 256];      // 32 KB
  __shared__ __align__(16) short P_lds[64 * 64];    // 8 KB swizzled; total 40960 B

  const int st_row = (l >> 5);
  const int st_ch  = (l & 31);

  bf16x8 qf[8];
  {
    const short* qrow = Qb + (size_t)(q0 + 16 * w + l15) * CCH + 8 * lhi;
    #pragma unroll
    for (int kk = 0; kk < 8; kk++) qf[kk] = *(const bf16x8*)(qrow + 32 * kk);
  }
  const f32x4 z4 = {0.f, 0.f, 0.f, 0.f};
  f32x4 oacc[4][4];
  #pragma unroll
  for (int qt = 0; qt < 4; qt++)
    #pragma unroll
    for (int ct = 0; ct < 4; ct++) oacc[qt][ct] = z4;
  float lpart[4] = {0.f, 0.f, 0.f, 0.f};

#define STAGE_K(M0) do { \
    _Pragma("unroll") \
    for (int r = 0; r < 8; r++){ \
      const int slot = 4 * r + w; \
      const int row = 2 * slot + st_row; \
      const int ch = st_ch ^ (row & 7); \
      gld_lds16(Kb + (size_t)((M0) + row) * CCH + (ch << 3), &Ks[slot * 512]); \
    } } while(0)

  // prologue: stage this half's tile 0
  STAGE_K(t0 * 64);

  #pragma unroll 1
  for (int t = t0; t < t0 + 18; t++){
    const int m0 = t * 64;
    __syncthreads();   // K(t) staged (drains vmcnt) & Ks free of prior readers

    // prefetch V tile into registers (consumed after second barrier)
    bf16x8 vfp[8];
    #pragma unroll
    for (int km = 0; km < 2; km++)
      #pragma unroll
      for (int ct = 0; ct < 4; ct++)
        vfp[4 * km + ct] = *(const bf16x8*)(Vb + (size_t)(64 * w + 16 * ct + l15) * NTOK + m0 + 32 * km + 8 * lhi);

    // S = Q·K^T from LDS (swizzled reads)
    f32x4 sacc[4] = {z4, z4, z4, z4};
    __builtin_amdgcn_s_setprio(1);
    #pragma unroll
    for (int mjb = 0; mjb < 4; mjb++){
      const int row = 16 * mjb + l15;
      const int rsw = row & 7;
      #pragma unroll
      for (int kk = 0; kk < 8; kk++){
        bf16x8 kf = *(const bf16x8*)(Ks + row * 256 + (((4 * kk + lhi) ^ rsw) << 3));
        sacc[mjb] = __builtin_amdgcn_mfma_f32_16x16x32_bf16(qf[kk], kf, sacc[mjb], 0, 0, 0);
      }
    }
    __builtin_amdgcn_s_setprio(0);
    // P = exp2(s'); per-lane partial row sums; swizzled P_lds write
    #pragma unroll
    for (int mjb = 0; mjb < 4; mjb++)
      #pragma unroll
      for (int r = 0; r < 4; r++){
        float p = exp2f(sacc[mjb][r]);
        lpart[r] += p;
        const int prow = 16 * w + 4 * lhi + r;
        const int pcol = 16 * mjb + l15;
        P_lds[prow * 64 + ((((pcol >> 3) ^ (prow & 7)) << 3) | (pcol & 7))] = f2bf(p);
      }
    __syncthreads();   // P visible AND all Ks reads done

    // stage K(t+1) now: completes during PV + next barrier wait
    if (t + 1 < t0 + 18) STAGE_K(m0 + 64);

    // O += P · V^T (P from swizzled LDS, V from prefetched regs)
    __builtin_amdgcn_s_setprio(1);
    #pragma unroll
    for (int km = 0; km < 2; km++){
      bf16x8 pf[4];
      #pragma unroll
      for (int qt = 0; qt < 4; qt++){
        const int prow = 16 * qt + l15;
        pf[qt] = *(const bf16x8*)&P_lds[prow * 64 + (((4 * km + lhi) ^ (prow & 7)) << 3)];
      }
      #pragma unroll
      for (int qt = 0; qt < 4; qt++)
        #pragma unroll
        for (int ct = 0; ct < 4; ct++)
          oacc[qt][ct] = __builtin_amdgcn_mfma_f32_16x16x32_bf16(pf[qt], vfp[4 * km + ct], oacc[qt][ct], 0, 0, 0);
    }
    __builtin_amdgcn_s_setprio(0);
  }
#undef STAGE_K

  // partial row-sums to global (butterfly over the 16-lane k-groups)
  const size_t hrow = ((size_t)half * NBATCH + b) * NTOK + q0;
  #pragma unroll
  for (int r = 0; r < 4; r++){
    float s = lpart[r];
    s += __shfl_xor(s, 1); s += __shfl_xor(s, 2); s += __shfl_xor(s, 4); s += __shfl_xor(s, 8);
    if (l15 == 0) lsumg[hrow + 16 * w + 4 * lhi + r] = s;
  }
  // partial O (bf16, unnormalized) to scratch
  short* Ob = Opart + hrow * CCH;
  #pragma unroll
  for (int qt = 0; qt < 4; qt++)
    #pragma unroll
    for (int ct = 0; ct < 4; ct++)
      #pragma unroll
      for (int r = 0; r < 4; r++)
        Ob[(size_t)(16 * qt + 4 * lhi + r) * CCH + 64 * w + 16 * ct + l15] = f2bf(oacc[qt][ct][r]);
}

// ---------------- combine split-KV partials: avT = (O0+O1)/(l0+l1) ----------------
__global__ __launch_bounds__(256) void reduce_kernel(const short* __restrict__ Op, const float* __restrict__ ls,
                                                     short* __restrict__ avT){
  const size_t HSZ = (size_t)NBATCH * NTOK * CCH;
  int idx = blockIdx.x * 256 + threadIdx.x;        // 1,179,648 threads
  int row = idx >> 5;                              // b*NTOK + n
  int c0 = (idx & 31) << 3;
  float inv = 1.0f / (ls[row] + ls[NBATCH * NTOK + row]);
  bf16x8 a = *(const bf16x8*)(Op + (size_t)row * CCH + c0);
  bf16x8 c = *(const bf16x8*)(Op + HSZ + (size_t)row * CCH + c0);
  bf16x8 o;
  #pragma unroll
  for (int j = 0; j < 8; j++)
    o[j] = f2bf((bf2f(a[j]) + bf2f(c[j])) * inv);
  *(bf16x8*)(avT + (size_t)row * CCH + c0) = o;
}

// ---------------- final: out = image + Wo·av + bo ----------------
__global__ __launch_bounds__(256) void final_kernel(const short* __restrict__ Wb, const short* __restrict__ avT,
                                                    const float* __restrict__ bo, const float* __restrict__ img,
                                                    float* __restrict__ out){
  __shared__ __align__(16) short As[128 * 64];
  __shared__ __align__(16) short Bs[128 * 64];
  const int b = blockIdx.y, bx = blockIdx.x;
  const int ti = bx / 18, tj = bx % 18;
  const short* Ablk = Wb + 3 * 65536 + (size_t)ti * 128 * CCH;
  const short* Bblk = avT + (size_t)b * NTOK * CCH + (size_t)tj * 128 * CCH;
  f32x4 acc[4][4];
  gemm128(Ablk, Bblk, As, Bs, acc);
  const int l = threadIdx.x & 63, w = threadIdx.x >> 6;
  const int l15 = l & 15, lhi = l >> 4, wi = w >> 1, wj = w & 1;
  const float* imgb = img + (size_t)b * CCH * NTOK;
  float* outb = out + (size_t)b * CCH * NTOK;
  #pragma unroll
  for (int mt = 0; mt < 4; mt++){
    const int i0 = ti * 128 + 64 * wi + 16 * mt + 4 * lhi;
    #pragma unroll
    for (int nt = 0; nt < 4; nt++){
      const int j = tj * 128 + 64 * wj + 16 * nt + l15;
      #pragma unroll
      for (int r = 0; r < 4; r++){
        const size_t idx = (size_t)(i0 + r) * NTOK + j;
        outb[idx] = acc[mt][nt][r] + bo[i0 + r] + imgb[idx];
      }
    }
  }
}

extern "C" void kernel_launch(void* const* d_in, const int* in_sizes, int n_in,
                              void* d_out, int out_size, void* d_ws, size_t ws_size,
                              hipStream_t stream) {
  const float* img = (const float*)d_in[0];
  const float* msk = (const float*)d_in[1];
  const float* Wq  = (const float*)d_in[2];
  const float* bq  = (const float*)d_in[3];
  const float* Wk  = (const float*)d_in[4];
  const float* bk  = (const float*)d_in[5];
  const float* Wv  = (const float*)d_in[6];
  const float* bv  = (const float*)d_in[7];
  const float* Wo  = (const float*)d_in[8];
  const float* bo  = (const float*)d_in[9];
  float* out = (float*)d_out;

  short* ws = (short*)d_ws;
  const size_t NE = (size_t)NBATCH * NTOK * CCH;
  short* imgT = ws;
  short* mskT = ws + NE;
  short* Qt   = ws + 2 * NE;
  short* Kt   = ws + 3 * NE;
  short* Vn   = ws + 4 * NE;
  short* Wb   = ws + 5 * NE;                    // 4 x 65536 bf16
  float* lsumg = (float*)(ws + 5 * NE + 4 * 65536);  // 2*16*2304 f32
  short* avT  = mskT;                           // reuse: mskT consumed before reduce writes avT
  short* Opart = (short*)d_out;                 // scratch: 2 bf16 halves = 37.7MB = d_out size

  cw_kernel<<<dim3(256), dim3(256), 0, stream>>>(Wq, Wk, Wv, Wo, Wb);
  prep_kernel<<<dim3(36, 4, 32), dim3(256), 0, stream>>>(img, msk, imgT, mskT);
  proj_kernel<<<dim3(36, 3, 16), dim3(256), 0, stream>>>(imgT, mskT, Wb, bq, bk, bv, Qt, Kt, Vn);
  attn_kernel<<<dim3(1152), dim3(256), 0, stream>>>(Qt, Kt, Vn, Opart, lsumg);
  reduce_kernel<<<dim3(4608), dim3(256), 0, stream>>>(Opart, lsumg, avT);
  final_kernel<<<dim3(36, 16), dim3(256), 0, stream>>>(Wb, avT, bo, img, out);
}